// Round 5
// baseline (403.727 us; speedup 1.0000x reference)
//
#include <hip/hip_runtime.h>

// Problem constants
constexpr int M_ROWS = 512;      // B*N keyword rows
constexpr int D_IN   = 768;
constexpr int T_DIM  = 512;
constexpr int V_SIZE = 49408;
constexpr int NV32   = V_SIZE / 32;  // 1544 vocab 32-tiles
constexpr int NK16   = T_DIM / 16;   // 32 k 16-blocks
constexpr float EPS  = 1e-8f;

typedef short bf16x8 __attribute__((ext_vector_type(8)));
typedef float f32x16 __attribute__((ext_vector_type(16)));

__device__ inline unsigned short bf16_rne(float f) {
  unsigned int u = __float_as_uint(f);
  u += 0x7FFFu + ((u >> 16) & 1u);
  return (unsigned short)(u >> 16);
}
__device__ inline float bf16_f32(unsigned short h) {
  return __uint_as_float(((unsigned int)h) << 16);
}
__device__ inline unsigned int f32_sortable(float f) {
  unsigned int u = __float_as_uint(f);
  return (u & 0x80000000u) ? ~u : (u | 0x80000000u);
}
__device__ inline unsigned long long shfl_xor_u64(unsigned long long x, int mask) {
  unsigned int lo = (unsigned int)(x & 0xFFFFFFFFull);
  unsigned int hi = (unsigned int)(x >> 32);
  lo = __shfl_xor(lo, mask);
  hi = __shfl_xor(hi, mask);
  return ((unsigned long long)hi << 32) | (unsigned long long)lo;
}

// MFMA 32x32x16 fragment address: slot-major [tile32*NK16 + k16][lane][8]
// lane = (rc & 31) | (((k >> 3) & 1) << 5), j = k & 7
__device__ inline size_t frag_idx(int tile_slot, int rc, int k) {
  return (size_t)tile_slot * 512 +
         (size_t)(((rc & 31) | (((k >> 3) & 1) << 5)) * 8) + (k & 7);
}

// ---------------- Kernel 1: proj kw = audio @ W + b -> bf16 hi/lo ----------------
// FRAG=1: fragment-ordered output (slot = (row>>5)*NK16 + (k>>4)); FRAG=0: row-major.
template <int FRAG>
__global__ __launch_bounds__(256) void proj_kernel(
    const float* __restrict__ audio, const float* __restrict__ W,
    const float* __restrict__ bias, unsigned short* __restrict__ kwH,
    unsigned short* __restrict__ kwL) {
  __shared__ float a[4][D_IN];  // 12 KB
  const int tid = threadIdx.x;
  const int m0 = blockIdx.x * 4;

  const float4* src4 = reinterpret_cast<const float4*>(audio + (size_t)m0 * D_IN);
  float4* a4 = reinterpret_cast<float4*>(&a[0][0]);
  #pragma unroll
  for (int i = 0; i < 3; ++i) a4[tid + 256 * i] = src4[tid + 256 * i];
  __syncthreads();

  const int t0 = tid, t1 = tid + 256;
  float acc[4][2] = {};
  #pragma unroll 4
  for (int d = 0; d < D_IN; ++d) {
    const float w0 = W[(size_t)d * T_DIM + t0];
    const float w1 = W[(size_t)d * T_DIM + t1];
    #pragma unroll
    for (int r = 0; r < 4; ++r) {
      acc[r][0] = fmaf(a[r][d], w0, acc[r][0]);
      acc[r][1] = fmaf(a[r][d], w1, acc[r][1]);
    }
  }
  const float b0 = bias[t0], b1 = bias[t1];
  #pragma unroll
  for (int r = 0; r < 4; ++r) {
    const int row = m0 + r;
    const float v0 = acc[r][0] + b0;
    const float v1 = acc[r][1] + b1;
    const unsigned short h0 = bf16_rne(v0);
    const unsigned short h1 = bf16_rne(v1);
    const unsigned short l0 = bf16_rne(v0 - bf16_f32(h0));
    const unsigned short l1 = bf16_rne(v1 - bf16_f32(h1));
    if (FRAG) {
      const size_t i0 = frag_idx((row >> 5) * NK16 + (t0 >> 4), row, t0);
      const size_t i1 = frag_idx((row >> 5) * NK16 + (t1 >> 4), row, t1);
      kwH[i0] = h0; kwH[i1] = h1;
      kwL[i0] = l0; kwL[i1] = l1;
    } else {
      kwH[(size_t)row * T_DIM + t0] = h0;
      kwH[(size_t)row * T_DIM + t1] = h1;
      kwL[(size_t)row * T_DIM + t0] = l0;
      kwL[(size_t)row * T_DIM + t1] = l1;
    }
  }
}

// ---------------- Kernel 2: split emb -> scaled bf16 hi/lo, fragment-ordered ----------------
// One block per 32 vocab rows. Phase 1: row inv-norms. Phase 2: convert + write frags.
__global__ __launch_bounds__(256) void split_kernel(
    const float* __restrict__ emb, unsigned short* __restrict__ embHf,
    unsigned short* __restrict__ embLf) {
  __shared__ float lds_inv[32];
  const int tid = threadIdx.x;
  const int v0 = blockIdx.x * 32;

  // phase 1: thread t covers row (t>>3), cols (t&7)*64 .. +64
  {
    const float* rp = emb + (size_t)(v0 + (tid >> 3)) * T_DIM + (tid & 7) * 64;
    const float4* rp4 = reinterpret_cast<const float4*>(rp);
    float ss = 0.0f;
    #pragma unroll
    for (int i = 0; i < 16; ++i) {
      const float4 x = rp4[i];
      ss += x.x * x.x + x.y * x.y + x.z * x.z + x.w * x.w;
    }
    ss += __shfl_xor(ss, 1);
    ss += __shfl_xor(ss, 2);
    ss += __shfl_xor(ss, 4);
    if ((tid & 7) == 0) lds_inv[tid >> 3] = 1.0f / fmaxf(sqrtf(ss), EPS);
  }
  __syncthreads();

  // phase 2: wave w writes k16 slots w*8 .. w*8+7 (tile is L2-hot from phase 1)
  const int w = tid >> 6, l = tid & 63;
  const float s = lds_inv[l & 31];
  const size_t gbase = (size_t)(v0 + (l & 31)) * T_DIM + (l >> 5) * 8;
  const size_t obase = (size_t)blockIdx.x * 32 * 512 + (size_t)l * 8;
  #pragma unroll
  for (int i = 0; i < 8; ++i) {
    const int k16 = w * 8 + i;
    const float4 x0 = *reinterpret_cast<const float4*>(&emb[gbase + k16 * 16]);
    const float4 x1 = *reinterpret_cast<const float4*>(&emb[gbase + k16 * 16 + 4]);
    const float xv[8] = {x0.x, x0.y, x0.z, x0.w, x1.x, x1.y, x1.z, x1.w};
    bf16x8 hv, lv;
    #pragma unroll
    for (int j = 0; j < 8; ++j) {
      const float x = xv[j] * s;
      const unsigned short h = bf16_rne(x);
      hv[j] = (short)h;
      lv[j] = (short)bf16_rne(x - bf16_f32(h));
    }
    *reinterpret_cast<bf16x8*>(&embHf[obase + (size_t)k16 * 512]) = hv;
    *reinterpret_cast<bf16x8*>(&embLf[obase + (size_t)k16 * 512]) = lv;
  }
}

// ---------------- Kernel 3: MFMA scoring + fused argmax (fragment-fed) ----------------
// BM=128 x BN=128, BK=32, dbuf LDS for B only (32 KB). 4 waves; wave w owns rows
// [m0+w*32, +32) x all 128 cols. A frags: coalesced 16B/lane register loads (L2-hot).
__global__ __launch_bounds__(256, 4) void score_kernel(
    const unsigned short* __restrict__ kwHf, const unsigned short* __restrict__ kwLf,
    const unsigned short* __restrict__ embHf, const unsigned short* __restrict__ embLf,
    unsigned long long* __restrict__ best) {
  __shared__ short ldsB[2][2][4][2][512];  // [buf][k16o][v32o][hl][lane*8+j] = 32 KB

  const int tid  = threadIdx.x;
  const int lane = tid & 63;
  const int w    = tid >> 6;
  const int xb   = blockIdx.x;        // vocab 128-tile: V32 tiles xb*4 .. xb*4+3
  const int m0   = blockIdx.y * 128;

  // staging: wave w loads slots idx = w*4+q; idx -> {hl, k16o, v32o}
  const unsigned short* gp[4];
  int ldsOff[4];
  #pragma unroll
  for (int q = 0; q < 4; ++q) {
    const int idx = w * 4 + q;
    const int hl = idx & 1, k16o = (idx >> 1) & 1, v32o = idx >> 2;
    const unsigned short* src = hl ? embLf : embHf;
    gp[q] = src + ((size_t)(xb * 4 + v32o) * NK16 + k16o) * 512 + (size_t)lane * 8;
    ldsOff[q] = ((k16o * 4 + v32o) * 2 + hl) * 512 + lane * 8;
  }

  // A fragment bases (kw fragment-ordered, R32-major)
  const unsigned short* aHp =
      kwHf + (size_t)((m0 >> 5) + w) * NK16 * 512 + (size_t)lane * 8;
  const unsigned short* aLp =
      kwLf + (size_t)((m0 >> 5) + w) * NK16 * 512 + (size_t)lane * 8;

  f32x16 acc[4];
  #pragma unroll
  for (int ct = 0; ct < 4; ++ct)
    #pragma unroll
    for (int i = 0; i < 16; ++i) acc[ct][i] = 0.0f;

  bf16x8 sreg[4];

  // prologue: stage chunk 0 into buf 0
  #pragma unroll
  for (int q = 0; q < 4; ++q) sreg[q] = *reinterpret_cast<const bf16x8*>(gp[q]);
  {
    short* b0 = &ldsB[0][0][0][0][0];
    #pragma unroll
    for (int q = 0; q < 4; ++q)
      *reinterpret_cast<bf16x8*>(b0 + ldsOff[q]) = sreg[q];
  }
  __syncthreads();

  for (int ci = 0; ci < 16; ++ci) {
    const int buf = ci & 1;

    // early-issue next-chunk staging loads (hide HBM/L3 latency under MFMA)
    if (ci < 15) {
      #pragma unroll
      for (int q = 0; q < 4; ++q)
        sreg[q] = *reinterpret_cast<const bf16x8*>(gp[q] + (size_t)(ci + 1) * 1024);
    }

    // A fragments for this chunk (coalesced 16B/lane from L2)
    bf16x8 aH[2], aL[2];
    #pragma unroll
    for (int ks = 0; ks < 2; ++ks) {
      aH[ks] = *reinterpret_cast<const bf16x8*>(aHp + (size_t)(ci * 2 + ks) * 512);
      aL[ks] = *reinterpret_cast<const bf16x8*>(aLp + (size_t)(ci * 2 + ks) * 512);
    }

    const short* bb = &ldsB[buf][0][0][0][0];
    #pragma unroll
    for (int ks = 0; ks < 2; ++ks) {
      #pragma unroll
      for (int ct = 0; ct < 4; ++ct) {
        const bf16x8 bH = *reinterpret_cast<const bf16x8*>(
            bb + ((ks * 4 + ct) * 2 + 0) * 512 + lane * 8);
        const bf16x8 bL = *reinterpret_cast<const bf16x8*>(
            bb + ((ks * 4 + ct) * 2 + 1) * 512 + lane * 8);
        acc[ct] = __builtin_amdgcn_mfma_f32_32x32x16_bf16(aH[ks], bH, acc[ct], 0, 0, 0);
        acc[ct] = __builtin_amdgcn_mfma_f32_32x32x16_bf16(aH[ks], bL, acc[ct], 0, 0, 0);
        acc[ct] = __builtin_amdgcn_mfma_f32_32x32x16_bf16(aL[ks], bH, acc[ct], 0, 0, 0);
      }
    }

    // write staged regs into the other buffer (its readers finished last barrier)
    if (ci < 15) {
      short* bn = &ldsB[buf ^ 1][0][0][0][0];
      #pragma unroll
      for (int q = 0; q < 4; ++q)
        *reinterpret_cast<bf16x8*>(bn + ldsOff[q]) = sreg[q];
    }
    __syncthreads();
  }

  // epilogue: argmax. C/D: col = lane&31, row = (reg&3) + 8*(reg>>2) + 4*(lane>>5)
  const int rowbase = m0 + w * 32 + 4 * (lane >> 5);
  #pragma unroll
  for (int reg = 0; reg < 16; ++reg) {
    const int row = rowbase + (reg & 3) + 8 * (reg >> 2);
    unsigned long long pk = 0;
    #pragma unroll
    for (int ct = 0; ct < 4; ++ct) {
      const float s = acc[ct][reg];
      const unsigned long long p =
          ((unsigned long long)f32_sortable(s) << 32) |
          (unsigned long long)(0xFFFFFFFFu - (unsigned)(xb * 128 + ct * 32 + (lane & 31)));
      if (p > pk) pk = p;
    }
    #pragma unroll
    for (int off = 1; off < 32; off <<= 1) {
      const unsigned long long o = shfl_xor_u64(pk, off);
      if (o > pk) pk = o;
    }
    if ((lane & 31) == 0) atomicMax(&best[row], pk);
  }
}

// ---------------- Fallback (R4) kernels: used only if ws is too small ----------------
__global__ __launch_bounds__(256) void norm_kernel(
    const float* __restrict__ emb, float* __restrict__ inv_norm) {
  const int wave = threadIdx.x >> 6;
  const int lane = threadIdx.x & 63;
  const int v = blockIdx.x * 4 + wave;
  const float4* row = reinterpret_cast<const float4*>(emb + (size_t)v * T_DIM);
  const float4 x = row[lane];
  const float4 y = row[lane + 64];
  float ss = x.x * x.x + x.y * x.y + x.z * x.z + x.w * x.w +
             y.x * y.x + y.y * y.y + y.z * y.z + y.w * y.w;
  #pragma unroll
  for (int off = 32; off > 0; off >>= 1) ss += __shfl_xor(ss, off);
  if (lane == 0) inv_norm[v] = 1.0f / fmaxf(sqrtf(ss), EPS);
}

__global__ __launch_bounds__(256, 2) void score_v1_kernel(
    const unsigned short* __restrict__ kwH, const unsigned short* __restrict__ kwL,
    const float* __restrict__ emb, const float* __restrict__ inv_norm,
    unsigned long long* __restrict__ best) {
  __shared__ short ldsH[2][8][64][8];
  __shared__ short ldsL[2][8][64][8];
  const int tid  = threadIdx.x;
  const int lane = tid & 63;
  const int w    = tid >> 6;
  const int n0   = blockIdx.x * 128;
  const int m0   = blockIdx.y * 256;
  size_t sg[2]; float ssc[2]; int sof[2];
  #pragma unroll
  for (int p = 0; p < 2; ++p) {
    const int s  = tid + 256 * p;
    const int ls = s & 63;
    const int nt = (s >> 6) & 3;
    const int ks = (s >> 8) & 1;
    const int col  = nt * 32 + (ls & 31);
    const int krel = ks * 16 + (ls >> 5) * 8;
    sg[p]  = (size_t)(n0 + col) * T_DIM + krel;
    ssc[p] = inv_norm[n0 + col];
    sof[p] = ((ks * 4 + nt) * 64 + ls) * 8;
  }
  const int kh = (lane >> 5) * 8;
  size_t aOff[2];
  #pragma unroll
  for (int rt = 0; rt < 2; ++rt)
    aOff[rt] = (size_t)(m0 + w * 64 + rt * 32 + (lane & 31)) * T_DIM + kh;
  f32x16 acc[2][4];
  #pragma unroll
  for (int rt = 0; rt < 2; ++rt)
    #pragma unroll
    for (int ct = 0; ct < 4; ++ct)
      #pragma unroll
      for (int i = 0; i < 16; ++i) acc[rt][ct][i] = 0.0f;
  float ld[2][8];
  #pragma unroll
  for (int p = 0; p < 2; ++p) {
    const float4 x0 = *reinterpret_cast<const float4*>(&emb[sg[p]]);
    const float4 x1 = *reinterpret_cast<const float4*>(&emb[sg[p] + 4]);
    ld[p][0] = x0.x; ld[p][1] = x0.y; ld[p][2] = x0.z; ld[p][3] = x0.w;
    ld[p][4] = x1.x; ld[p][5] = x1.y; ld[p][6] = x1.z; ld[p][7] = x1.w;
  }
  {
    short* hw = &ldsH[0][0][0][0];
    short* lw = &ldsL[0][0][0][0];
    #pragma unroll
    for (int p = 0; p < 2; ++p) {
      bf16x8 hv, lv;
      #pragma unroll
      for (int j = 0; j < 8; ++j) {
        const float x = ld[p][j] * ssc[p];
        const unsigned short h = bf16_rne(x);
        hv[j] = (short)h;
        lv[j] = (short)bf16_rne(x - bf16_f32(h));
      }
      *reinterpret_cast<bf16x8*>(hw + sof[p]) = hv;
      *reinterpret_cast<bf16x8*>(lw + sof[p]) = lv;
    }
  }
  __syncthreads();
  for (int ci = 0; ci < 16; ++ci) {
    const int buf = ci & 1;
    if (ci < 15) {
      #pragma unroll
      for (int p = 0; p < 2; ++p) {
        const size_t g = sg[p] + (size_t)(ci + 1) * 32;
        const float4 x0 = *reinterpret_cast<const float4*>(&emb[g]);
        const float4 x1 = *reinterpret_cast<const float4*>(&emb[g + 4]);
        ld[p][0] = x0.x; ld[p][1] = x0.y; ld[p][2] = x0.z; ld[p][3] = x0.w;
        ld[p][4] = x1.x; ld[p][5] = x1.y; ld[p][6] = x1.z; ld[p][7] = x1.w;
      }
    }
    const short* hq = &ldsH[buf][0][0][0];
    const short* lq = &ldsL[buf][0][0][0];
    #pragma unroll
    for (int ks = 0; ks < 2; ++ks) {
      const size_t ak = (size_t)(ci * 32 + ks * 16);
      bf16x8 aH[2], aL[2];
      #pragma unroll
      for (int rt = 0; rt < 2; ++rt) {
        aH[rt] = *reinterpret_cast<const bf16x8*>(&kwH[aOff[rt] + ak]);
        aL[rt] = *reinterpret_cast<const bf16x8*>(&kwL[aOff[rt] + ak]);
      }
      #pragma unroll
      for (int ct = 0; ct < 4; ++ct) {
        const bf16x8 bH = *reinterpret_cast<const bf16x8*>(hq + ((ks * 4 + ct) * 64 + lane) * 8);
        const bf16x8 bL = *reinterpret_cast<const bf16x8*>(lq + ((ks * 4 + ct) * 64 + lane) * 8);
        #pragma unroll
        for (int rt = 0; rt < 2; ++rt) {
          acc[rt][ct] = __builtin_amdgcn_mfma_f32_32x32x16_bf16(aH[rt], bH, acc[rt][ct], 0, 0, 0);
          acc[rt][ct] = __builtin_amdgcn_mfma_f32_32x32x16_bf16(aH[rt], bL, acc[rt][ct], 0, 0, 0);
          acc[rt][ct] = __builtin_amdgcn_mfma_f32_32x32x16_bf16(aL[rt], bH, acc[rt][ct], 0, 0, 0);
        }
      }
    }
    if (ci < 15) {
      short* hw = &ldsH[buf ^ 1][0][0][0];
      short* lw = &ldsL[buf ^ 1][0][0][0];
      #pragma unroll
      for (int p = 0; p < 2; ++p) {
        bf16x8 hv, lv;
        #pragma unroll
        for (int j = 0; j < 8; ++j) {
          const float x = ld[p][j] * ssc[p];
          const unsigned short h = bf16_rne(x);
          hv[j] = (short)h;
          lv[j] = (short)bf16_rne(x - bf16_f32(h));
        }
        *reinterpret_cast<bf16x8*>(hw + sof[p]) = hv;
        *reinterpret_cast<bf16x8*>(lw + sof[p]) = lv;
      }
    }
    __syncthreads();
  }
  #pragma unroll
  for (int rt = 0; rt < 2; ++rt) {
    const int rowbase = m0 + w * 64 + rt * 32 + 4 * (lane >> 5);
    #pragma unroll
    for (int reg = 0; reg < 16; ++reg) {
      const int row = rowbase + (reg & 3) + 8 * (reg >> 2);
      unsigned long long pk = 0;
      #pragma unroll
      for (int ct = 0; ct < 4; ++ct) {
        const float s = acc[rt][ct][reg];
        const unsigned long long p =
            ((unsigned long long)f32_sortable(s) << 32) |
            (unsigned long long)(0xFFFFFFFFu - (unsigned)(n0 + ct * 32 + (lane & 31)));
        if (p > pk) pk = p;
      }
      #pragma unroll
      for (int off = 1; off < 32; off <<= 1) {
        const unsigned long long o = shfl_xor_u64(pk, off);
        if (o > pk) pk = o;
      }
      if ((lane & 31) == 0) atomicMax(&best[row], pk);
    }
  }
}

// ---------------- Kernel 4: gather out[row] = token_emb[best[row]] ----------------
__global__ __launch_bounds__(128) void gather_kernel(
    const float* __restrict__ emb, const unsigned long long* __restrict__ best,
    float* __restrict__ out) {
  const int row = blockIdx.x;
  const unsigned int idx =
      0xFFFFFFFFu - (unsigned int)(best[row] & 0xFFFFFFFFull);
  const float4* src = reinterpret_cast<const float4*>(emb + (size_t)idx * T_DIM);
  float4* dst = reinterpret_cast<float4*>(out + (size_t)row * T_DIM);
  dst[threadIdx.x] = src[threadIdx.x];
}

// ---------------- launch ----------------
extern "C" void kernel_launch(void* const* d_in, const int* in_sizes, int n_in,
                              void* d_out, int out_size, void* d_ws, size_t ws_size,
                              hipStream_t stream) {
  const float* audio = (const float*)d_in[0];  // [512, 768]
  const float* Wp    = (const float*)d_in[1];  // [768, 512]
  const float* bp    = (const float*)d_in[2];  // [512]
  const float* emb   = (const float*)d_in[3];  // [49408, 512]
  float* out = (float*)d_out;                  // [512, 512]

  const size_t kw_elems  = (size_t)M_ROWS * T_DIM;          // 262144
  const size_t emb_elems = (size_t)V_SIZE * T_DIM;          // 25.3M
  const size_t need = 2 * kw_elems * 2 + 2 * emb_elems * 2 +
                      M_ROWS * sizeof(unsigned long long);  // ~102.3 MB

  char* ws = (char*)d_ws;
  if (ws_size >= need) {
    unsigned short* kwHf  = (unsigned short*)ws;
    unsigned short* kwLf  = kwHf + kw_elems;
    unsigned short* embHf = kwLf + kw_elems;
    unsigned short* embLf = embHf + emb_elems;
    unsigned long long* best = (unsigned long long*)(embLf + emb_elems);

    hipMemsetAsync(best, 0, M_ROWS * sizeof(unsigned long long), stream);
    proj_kernel<1><<<M_ROWS / 4, 256, 0, stream>>>(audio, Wp, bp, kwHf, kwLf);
    split_kernel<<<NV32, 256, 0, stream>>>(emb, embHf, embLf);
    score_kernel<<<dim3(V_SIZE / 128, M_ROWS / 128), 256, 0, stream>>>(
        kwHf, kwLf, embHf, embLf, best);
    gather_kernel<<<M_ROWS, 128, 0, stream>>>(emb, best, out);
  } else {
    // fallback: R4 path (~1.2 MB ws)
    unsigned short* kwH = (unsigned short*)ws;
    unsigned short* kwL = kwH + kw_elems;
    float* inv_norm = (float*)(kwL + kw_elems);
    unsigned long long* best = (unsigned long long*)(inv_norm + V_SIZE);

    hipMemsetAsync(best, 0, M_ROWS * sizeof(unsigned long long), stream);
    proj_kernel<0><<<M_ROWS / 4, 256, 0, stream>>>(audio, Wp, bp, kwH, kwL);
    norm_kernel<<<V_SIZE / 4, 256, 0, stream>>>(emb, inv_norm);
    score_v1_kernel<<<dim3(V_SIZE / 128, M_ROWS / 256), 256, 0, stream>>>(
        kwH, kwL, emb, inv_norm, best);
    gather_kernel<<<M_ROWS, 128, 0, stream>>>(emb, best, out);
  }
}

// Round 7
// 370.988 us; speedup vs baseline: 1.0882x; 1.0882x over previous
//
#include <hip/hip_runtime.h>

// Problem constants
constexpr int M_ROWS = 512;      // B*N keyword rows
constexpr int D_IN   = 768;
constexpr int T_DIM  = 512;
constexpr int V_SIZE = 49408;
constexpr int NV32   = V_SIZE / 32;  // 1544 vocab 32-tiles
constexpr int NK16   = T_DIM / 16;   // 32 k 16-blocks
constexpr float EPS  = 1e-8f;

typedef short bf16x8 __attribute__((ext_vector_type(8)));
typedef float f32x16 __attribute__((ext_vector_type(16)));

__device__ inline unsigned short bf16_rne(float f) {
  unsigned int u = __float_as_uint(f);
  u += 0x7FFFu + ((u >> 16) & 1u);
  return (unsigned short)(u >> 16);
}
__device__ inline float bf16_f32(unsigned short h) {
  return __uint_as_float(((unsigned int)h) << 16);
}
__device__ inline unsigned int f32_sortable(float f) {
  unsigned int u = __float_as_uint(f);
  return (u & 0x80000000u) ? ~u : (u | 0x80000000u);
}
__device__ inline unsigned long long shfl_xor_u64(unsigned long long x, int mask) {
  unsigned int lo = (unsigned int)(x & 0xFFFFFFFFull);
  unsigned int hi = (unsigned int)(x >> 32);
  lo = __shfl_xor(lo, mask);
  hi = __shfl_xor(hi, mask);
  return ((unsigned long long)hi << 32) | (unsigned long long)lo;
}

// MFMA 32x32x16 fragment address: slot-major [tile32*NK16 + k16][lane][8]
// lane = (rc & 31) | (((k >> 3) & 1) << 5), j = k & 7
__device__ inline size_t frag_idx(int tile_slot, int rc, int k) {
  return (size_t)tile_slot * 512 +
         (size_t)(((rc & 31) | (((k >> 3) & 1) << 5)) * 8) + (k & 7);
}

// ---------------- Kernel 1: fused prep = proj (blocks 0..127) + split (rest) ----
// proj: kw = audio @ W + b -> bf16 hi/lo, fragment-ordered.
// split: emb rows -> inv-norm-scaled bf16 hi/lo, fragment-ordered.
__global__ __launch_bounds__(256) void prep_kernel(
    const float* __restrict__ audio, const float* __restrict__ W,
    const float* __restrict__ bias, unsigned short* __restrict__ kwH,
    unsigned short* __restrict__ kwL, const float* __restrict__ emb,
    unsigned short* __restrict__ embHf, unsigned short* __restrict__ embLf) {
  __shared__ float a[4][D_IN];   // proj branch (12 KB)
  __shared__ float lds_inv[32];  // split branch
  const int tid = threadIdx.x;

  if (blockIdx.x < 128) {
    // ---- proj branch ----
    const int m0 = blockIdx.x * 4;
    const float4* src4 = reinterpret_cast<const float4*>(audio + (size_t)m0 * D_IN);
    float4* a4 = reinterpret_cast<float4*>(&a[0][0]);
    #pragma unroll
    for (int i = 0; i < 3; ++i) a4[tid + 256 * i] = src4[tid + 256 * i];
    __syncthreads();

    const int t0 = tid, t1 = tid + 256;
    float acc[4][2] = {};
    #pragma unroll 4
    for (int d = 0; d < D_IN; ++d) {
      const float w0 = W[(size_t)d * T_DIM + t0];
      const float w1 = W[(size_t)d * T_DIM + t1];
      #pragma unroll
      for (int r = 0; r < 4; ++r) {
        acc[r][0] = fmaf(a[r][d], w0, acc[r][0]);
        acc[r][1] = fmaf(a[r][d], w1, acc[r][1]);
      }
    }
    const float b0 = bias[t0], b1 = bias[t1];
    #pragma unroll
    for (int r = 0; r < 4; ++r) {
      const int row = m0 + r;
      const float v0 = acc[r][0] + b0;
      const float v1 = acc[r][1] + b1;
      const unsigned short h0 = bf16_rne(v0);
      const unsigned short h1 = bf16_rne(v1);
      const size_t i0 = frag_idx((row >> 5) * NK16 + (t0 >> 4), row, t0);
      const size_t i1 = frag_idx((row >> 5) * NK16 + (t1 >> 4), row, t1);
      kwH[i0] = h0; kwH[i1] = h1;
      kwL[i0] = bf16_rne(v0 - bf16_f32(h0));
      kwL[i1] = bf16_rne(v1 - bf16_f32(h1));
    }
  } else {
    // ---- split branch: one block per 32 vocab rows ----
    const int vb = blockIdx.x - 128;
    const int v0 = vb * 32;

    // phase 1: thread t covers row (t>>3), cols (t&7)*64 .. +64
    {
      const float* rp = emb + (size_t)(v0 + (tid >> 3)) * T_DIM + (tid & 7) * 64;
      const float4* rp4 = reinterpret_cast<const float4*>(rp);
      float ss = 0.0f;
      #pragma unroll
      for (int i = 0; i < 16; ++i) {
        const float4 x = rp4[i];
        ss += x.x * x.x + x.y * x.y + x.z * x.z + x.w * x.w;
      }
      ss += __shfl_xor(ss, 1);
      ss += __shfl_xor(ss, 2);
      ss += __shfl_xor(ss, 4);
      if ((tid & 7) == 0) lds_inv[tid >> 3] = 1.0f / fmaxf(sqrtf(ss), EPS);
    }
    __syncthreads();

    // phase 2: wave w writes k16 slots w*8 .. w*8+7 (tile is L2-hot from phase 1)
    const int w = tid >> 6, l = tid & 63;
    const float s = lds_inv[l & 31];
    const size_t gbase = (size_t)(v0 + (l & 31)) * T_DIM + (l >> 5) * 8;
    const size_t obase = (size_t)vb * 32 * 512 + (size_t)l * 8;
    #pragma unroll
    for (int i = 0; i < 8; ++i) {
      const int k16 = w * 8 + i;
      const float4 x0 = *reinterpret_cast<const float4*>(&emb[gbase + k16 * 16]);
      const float4 x1 = *reinterpret_cast<const float4*>(&emb[gbase + k16 * 16 + 4]);
      const float xv[8] = {x0.x, x0.y, x0.z, x0.w, x1.x, x1.y, x1.z, x1.w};
      bf16x8 hv, lv;
      #pragma unroll
      for (int j = 0; j < 8; ++j) {
        const float x = xv[j] * s;
        const unsigned short h = bf16_rne(x);
        hv[j] = (short)h;
        lv[j] = (short)bf16_rne(x - bf16_f32(h));
      }
      *reinterpret_cast<bf16x8*>(&embHf[obase + (size_t)k16 * 512]) = hv;
      *reinterpret_cast<bf16x8*>(&embLf[obase + (size_t)k16 * 512]) = lv;
    }
  }
}

// ---------------- Kernel 2: MFMA scoring + fused argmax ----------------
// BM=256 x BN=128, BK=32, dbuf B-only LDS (32 KB). 4 waves; wave w owns rows
// [m0 + w*64, +64) (rt=2 subtiles of 32) x 128 cols. Grid (2, 386), m fastest:
// the two m-halves of a vocab tile are dispatched adjacently -> emb frag tile
// fetched from HBM once, second block hits L3/L2.
__global__ __launch_bounds__(256, 2) void score_kernel(
    const unsigned short* __restrict__ kwHf, const unsigned short* __restrict__ kwLf,
    const unsigned short* __restrict__ embHf, const unsigned short* __restrict__ embLf,
    unsigned long long* __restrict__ best) {
  __shared__ short ldsB[2][16][512];  // [buf][(k16o*4+v32o)*2+hl][lane*8+j] = 32 KB

  const int tid  = threadIdx.x;
  const int lane = tid & 63;
  const int w    = tid >> 6;
  const int m0   = blockIdx.x * 256;  // 0 or 256
  const int yb   = blockIdx.y;        // vocab 128-tile: V32 tiles yb*4 .. yb*4+3

  // staging: wave w loads slots idx = w*4+q; idx -> {hl, k16o, v32o}
  const unsigned short* gp[4];
  int ldsOff[4];
  #pragma unroll
  for (int q = 0; q < 4; ++q) {
    const int idx = w * 4 + q;
    const int hl = idx & 1, k16o = (idx >> 1) & 1, v32o = idx >> 2;
    const unsigned short* src = hl ? embLf : embHf;
    gp[q] = src + ((size_t)(yb * 4 + v32o) * NK16 + k16o) * 512 + (size_t)lane * 8;
    ldsOff[q] = ((k16o * 4 + v32o) * 2 + hl) * 512 + lane * 8;
  }

  // A fragment bases: R32-tile = blockIdx.x*8 + w*2 + rt
  const unsigned short* aHp[2];
  const unsigned short* aLp[2];
  #pragma unroll
  for (int rt = 0; rt < 2; ++rt) {
    const size_t base =
        (size_t)(blockIdx.x * 8 + w * 2 + rt) * NK16 * 512 + (size_t)lane * 8;
    aHp[rt] = kwHf + base;
    aLp[rt] = kwLf + base;
  }

  f32x16 acc[2][4];
  #pragma unroll
  for (int rt = 0; rt < 2; ++rt)
    #pragma unroll
    for (int ct = 0; ct < 4; ++ct)
      #pragma unroll
      for (int i = 0; i < 16; ++i) acc[rt][ct][i] = 0.0f;

  bf16x8 sreg[4];

  // prologue: stage chunk 0 into buf 0
  #pragma unroll
  for (int q = 0; q < 4; ++q) sreg[q] = *reinterpret_cast<const bf16x8*>(gp[q]);
  {
    short* b0 = &ldsB[0][0][0];
    #pragma unroll
    for (int q = 0; q < 4; ++q)
      *reinterpret_cast<bf16x8*>(b0 + ldsOff[q]) = sreg[q];
  }
  __syncthreads();

  for (int ci = 0; ci < 16; ++ci) {
    const int buf = ci & 1;

    // early-issue next-chunk staging loads (hide memory latency under MFMA)
    if (ci < 15) {
      #pragma unroll
      for (int q = 0; q < 4; ++q)
        sreg[q] = *reinterpret_cast<const bf16x8*>(gp[q] + (size_t)(ci + 1) * 1024);
    }

    const short* bb = &ldsB[buf][0][0];
    #pragma unroll
    for (int ks = 0; ks < 2; ++ks) {
      // A fragments for this k16 (coalesced 16B/lane, L2/L3-hot)
      bf16x8 aH[2], aL[2];
      #pragma unroll
      for (int rt = 0; rt < 2; ++rt) {
        aH[rt] = *reinterpret_cast<const bf16x8*>(aHp[rt] + (size_t)(ci * 2 + ks) * 512);
        aL[rt] = *reinterpret_cast<const bf16x8*>(aLp[rt] + (size_t)(ci * 2 + ks) * 512);
      }
      #pragma unroll
      for (int ct = 0; ct < 4; ++ct) {
        const bf16x8 bH = *reinterpret_cast<const bf16x8*>(
            bb + ((ks * 4 + ct) * 2 + 0) * 512 + lane * 8);
        const bf16x8 bL = *reinterpret_cast<const bf16x8*>(
            bb + ((ks * 4 + ct) * 2 + 1) * 512 + lane * 8);
        #pragma unroll
        for (int rt = 0; rt < 2; ++rt) {
          acc[rt][ct] = __builtin_amdgcn_mfma_f32_32x32x16_bf16(aH[rt], bH, acc[rt][ct], 0, 0, 0);
          acc[rt][ct] = __builtin_amdgcn_mfma_f32_32x32x16_bf16(aH[rt], bL, acc[rt][ct], 0, 0, 0);
          acc[rt][ct] = __builtin_amdgcn_mfma_f32_32x32x16_bf16(aL[rt], bH, acc[rt][ct], 0, 0, 0);
        }
      }
    }

    // write staged regs into the other buffer (its readers finished last barrier)
    if (ci < 15) {
      short* bn = &ldsB[buf ^ 1][0][0];
      #pragma unroll
      for (int q = 0; q < 4; ++q)
        *reinterpret_cast<bf16x8*>(bn + ldsOff[q]) = sreg[q];
    }
    __syncthreads();
  }

  // epilogue: argmax. C/D: col = lane&31, row = (reg&3) + 8*(reg>>2) + 4*(lane>>5)
  #pragma unroll
  for (int rt = 0; rt < 2; ++rt) {
    const int rowbase = m0 + w * 64 + rt * 32 + 4 * (lane >> 5);
    #pragma unroll
    for (int reg = 0; reg < 16; ++reg) {
      const int row = rowbase + (reg & 3) + 8 * (reg >> 2);
      unsigned long long pk = 0;
      #pragma unroll
      for (int ct = 0; ct < 4; ++ct) {
        const float s = acc[rt][ct][reg];
        const unsigned long long p =
            ((unsigned long long)f32_sortable(s) << 32) |
            (unsigned long long)(0xFFFFFFFFu - (unsigned)(yb * 128 + ct * 32 + (lane & 31)));
        if (p > pk) pk = p;
      }
      #pragma unroll
      for (int off = 1; off < 32; off <<= 1) {
        const unsigned long long o = shfl_xor_u64(pk, off);
        if (o > pk) pk = o;
      }
      if ((lane & 31) == 0) atomicMax(&best[row], pk);
    }
  }
}

// ---------------- Fallback (R4) kernels: used only if ws is too small ----------------
template <int FRAG>
__global__ __launch_bounds__(256) void proj_kernel(
    const float* __restrict__ audio, const float* __restrict__ W,
    const float* __restrict__ bias, unsigned short* __restrict__ kwH,
    unsigned short* __restrict__ kwL) {
  __shared__ float a[4][D_IN];
  const int tid = threadIdx.x;
  const int m0 = blockIdx.x * 4;
  const float4* src4 = reinterpret_cast<const float4*>(audio + (size_t)m0 * D_IN);
  float4* a4 = reinterpret_cast<float4*>(&a[0][0]);
  #pragma unroll
  for (int i = 0; i < 3; ++i) a4[tid + 256 * i] = src4[tid + 256 * i];
  __syncthreads();
  const int t0 = tid, t1 = tid + 256;
  float acc[4][2] = {};
  #pragma unroll 4
  for (int d = 0; d < D_IN; ++d) {
    const float w0 = W[(size_t)d * T_DIM + t0];
    const float w1 = W[(size_t)d * T_DIM + t1];
    #pragma unroll
    for (int r = 0; r < 4; ++r) {
      acc[r][0] = fmaf(a[r][d], w0, acc[r][0]);
      acc[r][1] = fmaf(a[r][d], w1, acc[r][1]);
    }
  }
  const float b0 = bias[t0], b1 = bias[t1];
  #pragma unroll
  for (int r = 0; r < 4; ++r) {
    const int row = m0 + r;
    const float v0 = acc[r][0] + b0;
    const float v1 = acc[r][1] + b1;
    const unsigned short h0 = bf16_rne(v0);
    const unsigned short h1 = bf16_rne(v1);
    if (FRAG) {
      const size_t i0 = frag_idx((row >> 5) * NK16 + (t0 >> 4), row, t0);
      const size_t i1 = frag_idx((row >> 5) * NK16 + (t1 >> 4), row, t1);
      kwH[i0] = h0; kwH[i1] = h1;
      kwL[i0] = bf16_rne(v0 - bf16_f32(h0));
      kwL[i1] = bf16_rne(v1 - bf16_f32(h1));
    } else {
      kwH[(size_t)row * T_DIM + t0] = h0;
      kwH[(size_t)row * T_DIM + t1] = h1;
      kwL[(size_t)row * T_DIM + t0] = bf16_rne(v0 - bf16_f32(h0));
      kwL[(size_t)row * T_DIM + t1] = bf16_rne(v1 - bf16_f32(h1));
    }
  }
}

__global__ __launch_bounds__(256) void norm_kernel(
    const float* __restrict__ emb, float* __restrict__ inv_norm) {
  const int wave = threadIdx.x >> 6;
  const int lane = threadIdx.x & 63;
  const int v = blockIdx.x * 4 + wave;
  const float4* row = reinterpret_cast<const float4*>(emb + (size_t)v * T_DIM);
  const float4 x = row[lane];
  const float4 y = row[lane + 64];
  float ss = x.x * x.x + x.y * x.y + x.z * x.z + x.w * x.w +
             y.x * y.x + y.y * y.y + y.z * y.z + y.w * y.w;
  #pragma unroll
  for (int off = 32; off > 0; off >>= 1) ss += __shfl_xor(ss, off);
  if (lane == 0) inv_norm[v] = 1.0f / fmaxf(sqrtf(ss), EPS);
}

__global__ __launch_bounds__(256, 2) void score_v1_kernel(
    const unsigned short* __restrict__ kwH, const unsigned short* __restrict__ kwL,
    const float* __restrict__ emb, const float* __restrict__ inv_norm,
    unsigned long long* __restrict__ best) {
  __shared__ short ldsH[2][8][64][8];
  __shared__ short ldsL[2][8][64][8];
  const int tid  = threadIdx.x;
  const int lane = tid & 63;
  const int w    = tid >> 6;
  const int n0   = blockIdx.x * 128;
  const int m0   = blockIdx.y * 256;
  size_t sg[2]; float ssc[2]; int sof[2];
  #pragma unroll
  for (int p = 0; p < 2; ++p) {
    const int s  = tid + 256 * p;
    const int ls = s & 63;
    const int nt = (s >> 6) & 3;
    const int ks = (s >> 8) & 1;
    const int col  = nt * 32 + (ls & 31);
    const int krel = ks * 16 + (ls >> 5) * 8;
    sg[p]  = (size_t)(n0 + col) * T_DIM + krel;
    ssc[p] = inv_norm[n0 + col];
    sof[p] = ((ks * 4 + nt) * 64 + ls) * 8;
  }
  const int kh = (lane >> 5) * 8;
  size_t aOff[2];
  #pragma unroll
  for (int rt = 0; rt < 2; ++rt)
    aOff[rt] = (size_t)(m0 + w * 64 + rt * 32 + (lane & 31)) * T_DIM + kh;
  f32x16 acc[2][4];
  #pragma unroll
  for (int rt = 0; rt < 2; ++rt)
    #pragma unroll
    for (int ct = 0; ct < 4; ++ct)
      #pragma unroll
      for (int i = 0; i < 16; ++i) acc[rt][ct][i] = 0.0f;
  float ld[2][8];
  #pragma unroll
  for (int p = 0; p < 2; ++p) {
    const float4 x0 = *reinterpret_cast<const float4*>(&emb[sg[p]]);
    const float4 x1 = *reinterpret_cast<const float4*>(&emb[sg[p] + 4]);
    ld[p][0] = x0.x; ld[p][1] = x0.y; ld[p][2] = x0.z; ld[p][3] = x0.w;
    ld[p][4] = x1.x; ld[p][5] = x1.y; ld[p][6] = x1.z; ld[p][7] = x1.w;
  }
  {
    short* hw = &ldsH[0][0][0][0];
    short* lw = &ldsL[0][0][0][0];
    #pragma unroll
    for (int p = 0; p < 2; ++p) {
      bf16x8 hv, lv;
      #pragma unroll
      for (int j = 0; j < 8; ++j) {
        const float x = ld[p][j] * ssc[p];
        const unsigned short h = bf16_rne(x);
        hv[j] = (short)h;
        lv[j] = (short)bf16_rne(x - bf16_f32(h));
      }
      *reinterpret_cast<bf16x8*>(hw + sof[p]) = hv;
      *reinterpret_cast<bf16x8*>(lw + sof[p]) = lv;
    }
  }
  __syncthreads();
  for (int ci = 0; ci < 16; ++ci) {
    const int buf = ci & 1;
    if (ci < 15) {
      #pragma unroll
      for (int p = 0; p < 2; ++p) {
        const size_t g = sg[p] + (size_t)(ci + 1) * 32;
        const float4 x0 = *reinterpret_cast<const float4*>(&emb[g]);
        const float4 x1 = *reinterpret_cast<const float4*>(&emb[g + 4]);
        ld[p][0] = x0.x; ld[p][1] = x0.y; ld[p][2] = x0.z; ld[p][3] = x0.w;
        ld[p][4] = x1.x; ld[p][5] = x1.y; ld[p][6] = x1.z; ld[p][7] = x1.w;
      }
    }
    const short* hq = &ldsH[buf][0][0][0];
    const short* lq = &ldsL[buf][0][0][0];
    #pragma unroll
    for (int ks = 0; ks < 2; ++ks) {
      const size_t ak = (size_t)(ci * 32 + ks * 16);
      bf16x8 aH[2], aL[2];
      #pragma unroll
      for (int rt = 0; rt < 2; ++rt) {
        aH[rt] = *reinterpret_cast<const bf16x8*>(&kwH[aOff[rt] + ak]);
        aL[rt] = *reinterpret_cast<const bf16x8*>(&kwL[aOff[rt] + ak]);
      }
      #pragma unroll
      for (int ct = 0; ct < 4; ++ct) {
        const bf16x8 bH = *reinterpret_cast<const bf16x8*>(hq + ((ks * 4 + ct) * 64 + lane) * 8);
        const bf16x8 bL = *reinterpret_cast<const bf16x8*>(lq + ((ks * 4 + ct) * 64 + lane) * 8);
        #pragma unroll
        for (int rt = 0; rt < 2; ++rt) {
          acc[rt][ct] = __builtin_amdgcn_mfma_f32_32x32x16_bf16(aH[rt], bH, acc[rt][ct], 0, 0, 0);
          acc[rt][ct] = __builtin_amdgcn_mfma_f32_32x32x16_bf16(aH[rt], bL, acc[rt][ct], 0, 0, 0);
          acc[rt][ct] = __builtin_amdgcn_mfma_f32_32x32x16_bf16(aL[rt], bH, acc[rt][ct], 0, 0, 0);
        }
      }
    }
    if (ci < 15) {
      short* hw = &ldsH[buf ^ 1][0][0][0];
      short* lw = &ldsL[buf ^ 1][0][0][0];
      #pragma unroll
      for (int p = 0; p < 2; ++p) {
        bf16x8 hv, lv;
        #pragma unroll
        for (int j = 0; j < 8; ++j) {
          const float x = ld[p][j] * ssc[p];
          const unsigned short h = bf16_rne(x);
          hv[j] = (short)h;
          lv[j] = (short)bf16_rne(x - bf16_f32(h));
        }
        *reinterpret_cast<bf16x8*>(hw + sof[p]) = hv;
        *reinterpret_cast<bf16x8*>(lw + sof[p]) = lv;
      }
    }
    __syncthreads();
  }
  #pragma unroll
  for (int rt = 0; rt < 2; ++rt) {
    const int rowbase = m0 + w * 64 + rt * 32 + 4 * (lane >> 5);
    #pragma unroll
    for (int reg = 0; reg < 16; ++reg) {
      const int row = rowbase + (reg & 3) + 8 * (reg >> 2);
      unsigned long long pk = 0;
      #pragma unroll
      for (int ct = 0; ct < 4; ++ct) {
        const float s = acc[rt][ct][reg];
        const unsigned long long p =
            ((unsigned long long)f32_sortable(s) << 32) |
            (unsigned long long)(0xFFFFFFFFu - (unsigned)(n0 + ct * 32 + (lane & 31)));
        if (p > pk) pk = p;
      }
      #pragma unroll
      for (int off = 1; off < 32; off <<= 1) {
        const unsigned long long o = shfl_xor_u64(pk, off);
        if (o > pk) pk = o;
      }
      if ((lane & 31) == 0) atomicMax(&best[row], pk);
    }
  }
}

// ---------------- Kernel 3: gather out[row] = token_emb[best[row]] ----------------
__global__ __launch_bounds__(128) void gather_kernel(
    const float* __restrict__ emb, const unsigned long long* __restrict__ best,
    float* __restrict__ out) {
  const int row = blockIdx.x;
  const unsigned int idx =
      0xFFFFFFFFu - (unsigned int)(best[row] & 0xFFFFFFFFull);
  const float4* src = reinterpret_cast<const float4*>(emb + (size_t)idx * T_DIM);
  float4* dst = reinterpret_cast<float4*>(out + (size_t)row * T_DIM);
  dst[threadIdx.x] = src[threadIdx.x];
}

// ---------------- launch ----------------
extern "C" void kernel_launch(void* const* d_in, const int* in_sizes, int n_in,
                              void* d_out, int out_size, void* d_ws, size_t ws_size,
                              hipStream_t stream) {
  const float* audio = (const float*)d_in[0];  // [512, 768]
  const float* Wp    = (const float*)d_in[1];  // [768, 512]
  const float* bp    = (const float*)d_in[2];  // [512]
  const float* emb   = (const float*)d_in[3];  // [49408, 512]
  float* out = (float*)d_out;                  // [512, 512]

  const size_t kw_elems  = (size_t)M_ROWS * T_DIM;          // 262144
  const size_t emb_elems = (size_t)V_SIZE * T_DIM;          // 25.3M
  const size_t need = 2 * kw_elems * 2 + 2 * emb_elems * 2 +
                      M_ROWS * sizeof(unsigned long long);  // ~102.3 MB

  char* ws = (char*)d_ws;
  if (ws_size >= need) {
    unsigned short* kwHf  = (unsigned short*)ws;
    unsigned short* kwLf  = kwHf + kw_elems;
    unsigned short* embHf = kwLf + kw_elems;
    unsigned short* embLf = embHf + emb_elems;
    unsigned long long* best = (unsigned long long*)(embLf + emb_elems);

    hipMemsetAsync(best, 0, M_ROWS * sizeof(unsigned long long), stream);
    prep_kernel<<<128 + NV32, 256, 0, stream>>>(audio, Wp, bp, kwHf, kwLf,
                                                emb, embHf, embLf);
    score_kernel<<<dim3(M_ROWS / 256, V_SIZE / 128), 256, 0, stream>>>(
        kwHf, kwLf, embHf, embLf, best);
    gather_kernel<<<M_ROWS, 128, 0, stream>>>(emb, best, out);
  } else {
    // fallback: R4 path (~1.2 MB ws)
    unsigned short* kwH = (unsigned short*)ws;
    unsigned short* kwL = kwH + kw_elems;
    float* inv_norm = (float*)(kwL + kw_elems);
    unsigned long long* best = (unsigned long long*)(inv_norm + V_SIZE);

    hipMemsetAsync(best, 0, M_ROWS * sizeof(unsigned long long), stream);
    proj_kernel<0><<<M_ROWS / 4, 256, 0, stream>>>(audio, Wp, bp, kwH, kwL);
    norm_kernel<<<V_SIZE / 4, 256, 0, stream>>>(emb, inv_norm);
    score_v1_kernel<<<dim3(V_SIZE / 128, M_ROWS / 256), 256, 0, stream>>>(
        kwH, kwL, emb, inv_norm, best);
    gather_kernel<<<M_ROWS, 128, 0, stream>>>(emb, best, out);
  }
}